// Round 10
// baseline (125.914 us; speedup 1.0000x reference)
//
#include <hip/hip_runtime.h>

typedef unsigned short u16;
typedef unsigned int u32;
typedef __bf16 bf16x8 __attribute__((ext_vector_type(8)));
typedef float f32x16 __attribute__((ext_vector_type(16)));

#define C2 (-7.213475204444817f) /* -5/ln2 : exp(-5 t^2) = exp2(C2 t^2) */
#define T1C 0.28650480f          /* e^-1.25 */
#define T2C 0.0067379470f        /* e^-5    */

__device__ __forceinline__ u16 f2bf(float f) {
  u32 u = __float_as_uint(f);
  return (u16)((u + 0x7FFFu + ((u >> 16) & 1u)) >> 16);  // RNE
}

__device__ __forceinline__ f32x16 mfma16(uint4 a, uint4 b, f32x16 c) {
  return __builtin_amdgcn_mfma_f32_32x32x16_bf16(
      __builtin_bit_cast(bf16x8, a), __builtin_bit_cast(bf16x8, b), c, 0, 0, 0);
}

// ---------------------------------------------------------------------------
// Prep (unchanged; validated): f32 weights -> bf16, per-16k-chunk fragment
// order. wst3 granule(c, g) 16 B, g = s*256 + nq*64 + l:
//   content = W_s[k = c*16 + (l>>5)*8 + 0..8)[u = nq*32 + (l&31)]
// ---------------------------------------------------------------------------
__global__ __launch_bounds__(256) void kan_prep(const float* __restrict__ wb,
                                                const float* __restrict__ ws,
                                                u16* __restrict__ wst3) {
  __shared__ u16 tile[6][16][130];
  const int t = threadIdx.x;
  const int c = blockIdx.x;
#pragma unroll
  for (int it = 0; it < 8; ++it) {
    int idx = it * 256 + t;
    int d = idx >> 7, u = idx & 127;
    size_t base = (size_t)(c * 16 + d) * 128 + u;
    const float* p = ws + base * 8;
    float4 v0 = *(const float4*)p;
    float g4 = p[4];
    tile[0][d][u] = f2bf(v0.x);
    tile[1][d][u] = f2bf(v0.y);
    tile[2][d][u] = f2bf(v0.z);
    tile[3][d][u] = f2bf(v0.w);
    tile[4][d][u] = f2bf(g4);
    tile[5][d][u] = f2bf(wb[base]);
  }
  __syncthreads();
#pragma unroll
  for (int i = 0; i < 6; ++i) {
    int g = i * 256 + t;
    int s = g >> 8, r = g & 255;
    int nq = r >> 6, l = r & 63;
    int u = nq * 32 + (l & 31);
    int dbase = (l >> 5) * 8;
    u32 q[4];
#pragma unroll
    for (int j = 0; j < 4; ++j) {
      u32 lo = tile[s][dbase + 2 * j][u];
      u32 hi = tile[s][dbase + 2 * j + 1][u];
      q[j] = lo | (hi << 16);
    }
    uint4 w4; w4.x = q[0]; w4.y = q[1]; w4.z = q[2]; w4.w = q[3];
    *(uint4*)(wst3 + (size_t)c * 12288 + (size_t)g * 8) = w4;
  }
}

// ---------------------------------------------------------------------------
// Main R17 = R16 + A-REGISTER PING-PONG.  R16's counters fit a fully
// SERIALIZED pipe model (MFMA 10.3 + LDS 19 + L2 12 + VALU 7 ~= 48 ~= 44.5
// measured): each phase waits for its 12 ds_reads, then MFMAs.  Fix: per
// phase issue next chunk's B (vmem) AND next phase's A (ds) into alternate
// register sets, then MFMA on current sets -> counted lgkm waits, LDS
// service overlaps MFMA.  Phase 0 of each body stays exposed (dbuf+barrier
// forbids crossing; ~300cyc/body accepted).
// All else verbatim R16/R11 (validated): producers waves 0..3 (rbf once ->
// LDS dbuf 2x48KB, PBAR = lgkmcnt(0)+s_barrier, x prefetch in flight
// across barriers); consumers waves 4..7 (wn = n-quad, full K, acc 64 AGPR,
// raw RBAR, setprio around MFMA).  A granule (s,g,p,kh): byte s*8192 +
// (g*4+p)*1024 + kh*512 + ((m^(p*2+kh))&31)*16;  B: chunk c: c*24576 +
// s*4096 + wn*1024 + lane*16;  mfma A[m=lane&31][k=(lane>>5)*8+j];
// C/D col=lane&31, row=(reg&3)+8*(reg>>2)+4*(lane>>5).
// Registers: consumer ~= 96 A-pp + 48 B-pp + 64 AGPR + misc ~= 245 <= 256
// at (512,2).  WRITE_SIZE is the spill alarm (expect 8.2 MB).
// ---------------------------------------------------------------------------
#define RBAR()                            \
  do {                                    \
    __builtin_amdgcn_s_barrier();         \
    __builtin_amdgcn_sched_barrier(0);    \
  } while (0)
#define PBAR()                                          \
  do {                                                  \
    asm volatile("s_waitcnt lgkmcnt(0)" ::: "memory");  \
    __builtin_amdgcn_s_barrier();                       \
    __builtin_amdgcn_sched_barrier(0);                  \
  } while (0)

__global__ __launch_bounds__(512, 2) void kan_main(const float* __restrict__ x,
                                                   const u16* __restrict__ wst3,
                                                   float* __restrict__ out) {
  __shared__ __align__(16) char lds[98304];  // 2 x 49152

  const int t = threadIdx.x;
  const int lane = t & 63;
  const int w = t >> 6;
  const int b0 = blockIdx.x * 64;

  if (w < 4) {
    // ================= PRODUCERS (verbatim R16) =================
    const int pid = (w << 6) + lane;  // 0..255
    const int r0 = pid >> 3;          // 0..31
    const int o = pid & 7;            // k-octet within BK=64 body
    const u32 aw0 = ((u32)(o >> 1) << 10) + ((u32)(o & 1) << 9) +
                    ((u32)((r0 ^ o) & 31) << 4);
    const u32 aw1 = aw0 + 4096;  // g=1 (rows 32..63)
    const float* xpA = x + (size_t)(b0 + r0) * 1024 + o * 8;
    const float* xpB = xpA + 32 * 1024;

    auto rbf6 = [&](char* buf, u32 aw, float4 xa, float4 xb) {
      float xf[8] = {xa.x, xa.y, xa.z, xa.w, xb.x, xb.y, xb.z, xb.w};
      u32 pk[6][4];
#pragma unroll
      for (int pp = 0; pp < 4; ++pp) {
        u32 lo6[6], hi6[6];
#pragma unroll
        for (int e = 0; e < 2; ++e) {
          float xv = xf[2 * pp + e];
          float t0 = C2 * xv;
          float P = __builtin_amdgcn_exp2f(t0 * xv);  // e^{-5x^2}
          float Qp = __builtin_amdgcn_exp2f(-t0);     // e^{+5x}
          float Qm = __builtin_amdgcn_exp2f(t0);      // e^{-5x}
          float PQ = P * Qp, PQm = P * Qm;
          u32* dst = e ? hi6 : lo6;
          dst[0] = __float_as_uint(PQm * Qm * T2C) + 0x8000u;
          dst[1] = __float_as_uint(PQm * T1C) + 0x8000u;
          dst[2] = __float_as_uint(P) + 0x8000u;
          dst[3] = __float_as_uint(PQ * T1C) + 0x8000u;
          dst[4] = __float_as_uint(PQ * Qp * T2C) + 0x8000u;
          dst[5] = __float_as_uint(xv) + 0x8000u;
        }
#pragma unroll
        for (int s = 0; s < 6; ++s)
          pk[s][pp] = __builtin_amdgcn_perm(hi6[s], lo6[s], 0x07060302);
      }
#pragma unroll
      for (int s = 0; s < 6; ++s) {
        uint4 v; v.x = pk[s][0]; v.y = pk[s][1]; v.z = pk[s][2]; v.w = pk[s][3];
        *(uint4*)(buf + s * 8192 + aw) = v;
      }
    };

    float4 xA0 = *(const float4*)(xpA);
    float4 xA1 = *(const float4*)(xpA + 4);
    float4 xB0 = *(const float4*)(xpB);
    float4 xB1 = *(const float4*)(xpB + 4);
    rbf6(lds, aw0, xA0, xA1);
    rbf6(lds, aw1, xB0, xB1);
    xA0 = *(const float4*)(xpA + 64);
    xA1 = *(const float4*)(xpA + 68);
    xB0 = *(const float4*)(xpB + 64);
    xB1 = *(const float4*)(xpB + 68);
    PBAR();  // prologue barrier

    for (int i = 0; i < 16; ++i) {
      if (i < 15) {
        char* nxt = lds + ((i + 1) & 1) * 49152;
        rbf6(nxt, aw0, xA0, xA1);
        rbf6(nxt, aw1, xB0, xB1);
        if (i < 14) {
          xA0 = *(const float4*)(xpA + (i + 2) * 64);
          xA1 = *(const float4*)(xpA + (i + 2) * 64 + 4);
          xB0 = *(const float4*)(xpB + (i + 2) * 64);
          xB1 = *(const float4*)(xpB + (i + 2) * 64 + 4);
        }
      }
      PBAR();  // per-body barriers (x prefetch stays in flight)
    }
    __syncthreads();  // final rendezvous
  } else {
    // ================= CONSUMERS =================
    const int wn = w - 4;  // n-quad: cols wn*32 .. +32
    const int m = lane & 31, kh = lane >> 5;
    u32 aoff[4];
#pragma unroll
    for (int p = 0; p < 4; ++p)
      aoff[p] = (u32)(p * 1024 + kh * 512 + (((m ^ (p * 2 + kh)) & 31) << 4));
    const char* bb = (const char*)wst3 + wn * 1024 + lane * 16;

    auto ldB = [&](int chunk, uint4* dst) {
      const char* bc = bb + (size_t)chunk * 24576;
#pragma unroll
      for (int s = 0; s < 6; ++s) dst[s] = *(const uint4*)(bc + s * 4096);
    };
    // A fragment set for phase p: dst[0..5] = g0 slabs, dst[6..11] = g1
    auto ldA = [&](const char* cur, int p, uint4* dst) {
#pragma unroll
      for (int s = 0; s < 6; ++s) {
        dst[s] = *(const uint4*)(cur + s * 8192 + aoff[p]);
        dst[6 + s] = *(const uint4*)(cur + s * 8192 + 4096 + aoff[p]);
      }
    };

    f32x16 acc[4];  // [0,1]=spline g0/g1, [2,3]=base g0/g1
#pragma unroll
    for (int i = 0; i < 4; ++i)
#pragma unroll
      for (int jj = 0; jj < 16; ++jj) acc[i][jj] = 0.f;

    uint4 bvE[6], bvO[6];    // B ping-pong (even/odd chunk)
    uint4 avE[12], avO[12];  // A ping-pong (even/odd phase)
    ldB(0, bvE);             // chunk 0 in flight across prologue barrier

    RBAR();  // prologue barrier

    for (int i = 0; i < 16; ++i) {
      const char* cur = lds + (i & 1) * 49152;
      ldA(cur, 0, avE);  // phase-0 reads (exposed; can't cross dbuf barrier)
#pragma unroll
      for (int p = 0; p < 4; ++p) {
        uint4* bcur = (p & 1) ? bvO : bvE;
        uint4* bnxt = (p & 1) ? bvE : bvO;
        uint4* acur = (p & 1) ? avO : avE;
        uint4* anxt = (p & 1) ? avE : avO;
        int cn = i * 4 + p + 1; if (cn > 63) cn = 63;
        ldB(cn, bnxt);                  // next-chunk B: 1 phase of cover
        if (p < 3) ldA(cur, p + 1, anxt);  // next-phase A: overlaps MFMAs
        __builtin_amdgcn_s_setprio(1);
#pragma unroll
        for (int s = 0; s < 5; ++s) {
          acc[0] = mfma16(acur[s], bcur[s], acc[0]);
          acc[1] = mfma16(acur[6 + s], bcur[s], acc[1]);
        }
        acc[2] = mfma16(acur[5], bcur[5], acc[2]);
        acc[3] = mfma16(acur[11], bcur[5], acc[3]);
        __builtin_amdgcn_s_setprio(0);
      }
      RBAR();  // per-body barriers (B loads stay in flight)
    }

    // ---- epilogue: full-K acc, no merge; direct silu+add+store
    const int col = wn * 32 + (lane & 31);
    __syncthreads();  // final rendezvous (matches producer tail)
#pragma unroll
    for (int g = 0; g < 2; ++g) {
#pragma unroll
      for (int reg = 0; reg < 16; ++reg) {
        int row = g * 32 + (reg & 3) + 8 * (reg >> 2) + 4 * (lane >> 5);
        float z = acc[2 + g][reg];
        float sv = z / (1.0f + __expf(-z));
        out[(size_t)(b0 + row) * 128 + col] = sv + acc[g][reg];
      }
    }
  }
}

extern "C" void kernel_launch(void* const* d_in, const int* in_sizes, int n_in,
                              void* d_out, int out_size, void* d_ws, size_t ws_size,
                              hipStream_t stream) {
  const float* x  = (const float*)d_in[0];   // [16384][1024] f32
  const float* wb = (const float*)d_in[1];   // [1024][128]   f32
  const float* ws = (const float*)d_in[2];   // [1024][128][8] f32
  u16* wst3 = (u16*)d_ws;                    // [64][1536] granules, 1.5 MB
  float* out = (float*)d_out;                // [16384][128]  f32

  kan_prep<<<dim3(64), 256, 0, stream>>>(wb, ws, wst3);
  kan_main<<<dim3(256), 512, 0, stream>>>(x, wst3, out);
}